// Round 11
// baseline (43348.639 us; speedup 1.0000x reference)
//
#include <hip/hip_runtime.h>
#include <hip/hip_bf16.h>
#include <stdint.h>

#define NS 4096     // samples / time steps
#define DT 1024     // dim_t == hidden == in
#define H4 4096     // 4*HID

// ---------- math helpers ----------
__device__ __forceinline__ float sigm_f(float x) { return 1.f / (1.f + __expf(-x)); }
__device__ __forceinline__ float tanh_f(float x) {
    float ax = fminf(fabsf(x), 15.f);                 // overflow-safe
    float t = 1.f - 2.f / (__expf(2.f * ax) + 1.f);
    return copysignf(t, x);
}

// ---------- sinusoidal embedding ----------
__global__ void emb_kernel(const int* __restrict__ ts, float* __restrict__ emb) {
    int t = blockIdx.x;
    int i = threadIdx.x;                 // 0..511
    float tv = (float)ts[t];
    const float c = -0.018024149455922082f;  // -ln(10000)/511
    float f = __expf(c * (float)i);
    float a = tv * f;
    float s, co;
    sincosf(a, &s, &co);
    emb[(size_t)t * DT + i] = s;
    emb[(size_t)t * DT + 512 + i] = co;
}

// ---------- generic C = A(M,K) @ B(Nc,K)^T + bias [+bias2] [+skip] [silu] ----------
// BM=128, BN=64, BK=16, 256 threads, each thread 8x4 outputs.
// XGMODE: 0 = plain fp32 C; 1 = bf16 XG layout; 2 = fp32 XG layout.
// XG layout per epoch (4096 elems): pos = k*16 + r*4 + q for col = q*1024 + 4k + r.
template <bool SILU, bool SKIP, int XGMODE>
__global__ __launch_bounds__(256) void gemm_bt(
    const float* __restrict__ A, const float* __restrict__ B,
    const float* __restrict__ bias, const float* __restrict__ bias2,
    const float* __restrict__ skip, float* __restrict__ Cf,
    __hip_bfloat16* __restrict__ Cb, int M, int Nc, int K)
{
    __shared__ __align__(16) float As[16][132];
    __shared__ __align__(16) float Bs[16][68];
    const int bn = blockIdx.x, bm = blockIdx.y, lz = blockIdx.z;
    if (XGMODE) {
        B     += (size_t)lz * H4 * DT;
        bias  += (size_t)lz * H4;
        bias2 += (size_t)lz * H4;
    }
    const int tid = threadIdx.x;
    const int tr = tid >> 4, tc = tid & 15;
    const int alr = tid >> 1, alc = (tid & 1) << 3;   // A: 128 rows x 16 cols
    const int blr = tid >> 2, blc = (tid & 3) << 2;   // B: 64 rows x 16 cols
    const float* Ap = A + (size_t)(bm * 128 + alr) * K + alc;
    const float* Bp = B + (size_t)(bn * 64 + blr) * K + blc;

    float acc[8][4];
#pragma unroll
    for (int i = 0; i < 8; i++)
#pragma unroll
        for (int j = 0; j < 4; j++) acc[i][j] = 0.f;

    for (int kk = 0; kk < K; kk += 16) {
        float4 a0 = *(const float4*)(Ap + kk);
        float4 a1 = *(const float4*)(Ap + kk + 4);
        float4 b0 = *(const float4*)(Bp + kk);
        __syncthreads();
        As[alc + 0][alr] = a0.x; As[alc + 1][alr] = a0.y;
        As[alc + 2][alr] = a0.z; As[alc + 3][alr] = a0.w;
        As[alc + 4][alr] = a1.x; As[alc + 5][alr] = a1.y;
        As[alc + 6][alr] = a1.z; As[alc + 7][alr] = a1.w;
        Bs[blc + 0][blr] = b0.x; Bs[blc + 1][blr] = b0.y;
        Bs[blc + 2][blr] = b0.z; Bs[blc + 3][blr] = b0.w;
        __syncthreads();
#pragma unroll
        for (int k = 0; k < 16; k++) {
            const float4 av0 = *(const float4*)&As[k][tr * 8];
            const float4 av1 = *(const float4*)&As[k][tr * 8 + 4];
            const float4 bv  = *(const float4*)&Bs[k][tc * 4];
            float aa[8] = {av0.x, av0.y, av0.z, av0.w, av1.x, av1.y, av1.z, av1.w};
            float bb[4] = {bv.x, bv.y, bv.z, bv.w};
#pragma unroll
            for (int i = 0; i < 8; i++)
#pragma unroll
                for (int j = 0; j < 4; j++)
                    acc[i][j] = fmaf(aa[i], bb[j], acc[i][j]);
        }
    }

#pragma unroll
    for (int i = 0; i < 8; i++) {
        int row = bm * 128 + tr * 8 + i;
#pragma unroll
        for (int j = 0; j < 4; j++) {
            int col = bn * 64 + tc * 4 + j;
            float v = acc[i][j] + bias[col];
            if (XGMODE) v += bias2[col];
            if (SKIP)   v += skip[(size_t)row * Nc + col];
            if (SILU)   v = v * (1.f / (1.f + __expf(-v)));
            if (XGMODE) {
                int q = col >> 10, jj = col & 1023;
                size_t idx = (size_t)row * 16384 + (size_t)lz * 4096
                           + ((size_t)(jj >> 2) << 4) + ((jj & 3) << 2) + q;
                if (XGMODE == 2) Cf[idx] = v;
                else             Cb[idx] = __float2bfloat16(v);
            } else {
                Cf[(size_t)row * Nc + col] = v;
            }
        }
    }
}

// ---------- persistent sequential LSTM chain ----------
// r0 STRUCTURE + r7/r9 private-line hbuf + r10 WAVE-AFFINITY STAGING.
// 256 WGs x 256 threads; WG k owns h/c rows [4k,4k+4).
// r10 change: wave w polls AND stages exactly lh block w (rows
// [256w,256w+256), 4 words/lane). The dot of thread (w,cg) reads only
// lh[(w<<8)+(cg<<6) .. +64) -- staged by its OWN wave -> lh block w is
// wave-private every epoch:
//   * B1 deleted (in-wave ds_write->ds_read ordered by compiler lgkmcnt
//     on the aliasing array + wave lockstep reconvergence after the poll
//     loop; no cross-wave lh sharing)
//   * each wave starts its dot as soon as ITS 256 rows arrive -- early
//     waves' dot hides under late waves' detect (the old B1 convoy made
//     the whole block wait for the globally-last word)
// lds_p is parity-double-buffered [2][64]: waves desync only within the
// B2(e)->B2(e+1) window; fast wave writes parity (e+1)&1 while gate
// threads read e&1 -- disjoint. B2 still orders within the epoch.
// Dot mapping (broadcast, r0): lane = (j=t&15, cg=(t>>4)&3), wave w; 16
// lanes/address -> free broadcast; rotation (i+4cg)&15 -> 2-way residual.
// Cross-wave reduce via lds_p + B2; gates+publish by t<4 -> one coalesced
// 32B store into WG k's PRIVATE 128B line (sole writer, r7-verified).
// Poll word for row r: ((r>>2)<<4) + (r&3); wave-affinity rows
// r = (w<<8)+(m<<6)+lam -> word (w<<10)+(m<<8)+((lam>>2)<<4)+(lam&3).
// Evidence trail: r3 WRITE_SIZE verified; r5 poll-rate/fold null; r6
// regsPerBlock cap at 1024 thr; r7/r9 private lines -0.8..-3.4ms; r9 =
// 39.24ms steady (5745 cy/epoch, poll-spin dominated per VALUBusy).
// Deadlock-free: hbuf slot for epoch e overwritten only at e+2 (requires
// all WGs published e+1, requires all consumed e) -- invariant unchanged;
// affinity only remaps WHO polls each word.
template <typename XT>
__global__ __launch_bounds__(256, 1) void seq_kernel(
    const float* __restrict__ Whh,            // [4][4096][1024]
    const XT* __restrict__ XG,                // [epoch][k*16 + r*4 + q]
    float* __restrict__ hall,                 // [4096][1024]
    uint64_t* hbuf)                           // [2][256][16]
{
    const int k = blockIdx.x;
    const int t = threadIdx.x;
    const int j = t & 15;                     // g-row index d
    const int cg = (t >> 4) & 3;              // 64-col sub-chunk
    const int w = t >> 6;                     // wave id
    const int lam = t & 63;                   // lane id
    const int q = j & 3, r = j >> 2;
    const int grow = q * 1024 + 4 * k + r;

    // weights, rotated to match the rotated LDS reads:
    // wreg[l][i*4+e] = Whh[l][grow][256w + 64cg + 4*((i+4cg)&15) + e]
    float wreg[4][64];
#pragma unroll
    for (int l = 0; l < 4; l++) {
        const float* src = Whh + ((size_t)l * H4 + grow) * 1024 + (w << 8) + (cg << 6);
#pragma unroll
        for (int i = 0; i < 16; i++) {
            int ii = (i + 4 * cg) & 15;
            float4 v = *(const float4*)(src + (ii << 2));
            wreg[l][i * 4 + 0] = v.x; wreg[l][i * 4 + 1] = v.y;
            wreg[l][i * 4 + 2] = v.z; wreg[l][i * 4 + 3] = v.w;
        }
    }

    __shared__ __align__(16) float lh[1024];      // block w is wave-w-private
    __shared__ __align__(16) float lds_p[2][64];  // epoch-parity partials
    float creg = 0.f;   // c for row 4k+t (threads t<4 only)

    // wave-affinity poll word base: row r = (w<<8)+(m<<6)+lam
    //   -> word (w<<10) + (m<<8) + ((lam>>2)<<4) + (lam&3)
    const int pw = (w << 10) + ((lam >> 2) << 4) + (lam & 3);
    const int lhb = (w << 8) + lam;               // lh stage base (+ m<<6)

    for (int step = 0; step < NS; ++step) {
#pragma unroll
        for (int l = 0; l < 4; l++) {
            const int it = step * 4 + l + 1;             // epoch being produced
            const uint32_t rtag = (uint32_t)(it - 1);
            uint64_t* rb = (l & 1) ? (hbuf + 4096) : hbuf;        // (it-1)&1 == l&1
            uint64_t* wb = ((l + 1) & 1) ? (hbuf + 4096) : hbuf;  // it&1
            float* lp = lds_p[it & 1];

            // ---- XG prefetch by gate threads, issued BEFORE polling
            float xg0 = 0.f, xg1 = 0.f, xg2 = 0.f, xg3 = 0.f;
            if (t < 4) {
                const XT* p = XG + (size_t)(it - 1) * H4 + (k << 4) + (t << 2);
                if constexpr (sizeof(XT) == 4) {
                    float4 v = *(const float4*)p;
                    xg0 = v.x; xg1 = v.y; xg2 = v.z; xg3 = v.w;
                } else {
                    ushort4 v = *(const ushort4*)p;
                    xg0 = __uint_as_float((uint32_t)v.x << 16);
                    xg1 = __uint_as_float((uint32_t)v.y << 16);
                    xg2 = __uint_as_float((uint32_t)v.z << 16);
                    xg3 = __uint_as_float((uint32_t)v.w << 16);
                }
            }

            // ---- wave-affinity poll + stage: lane lam of wave w owns rows
            //      (w<<8)+(m<<6)+lam, m=0..3 (all in lh block w)
            uint32_t got = 0;
            while (got != 0xFu) {
#pragma unroll
                for (int m = 0; m < 4; m++) {
                    if (!(got & (1u << m))) {
                        uint64_t u = __hip_atomic_load(&rb[pw + (m << 8)],
                                                       __ATOMIC_RELAXED, __HIP_MEMORY_SCOPE_AGENT);
                        if ((uint32_t)u == rtag) {
                            lh[lhb + (m << 6)] = __uint_as_float((uint32_t)(u >> 32));
                            got |= (1u << m);
                        }
                    }
                }
            }
            // no B1: lh block w staged entirely by this wave (lockstep +
            // compiler-inserted lgkmcnt orders the ds_write->ds_read)

            // ---- broadcast dot: 16 lanes/address, rotated, 4 accumulators
            const float* hbase = lh + (w << 8) + (cg << 6);
            float a0 = 0.f, a1 = 0.f, a2 = 0.f, a3 = 0.f;
#pragma unroll
            for (int i = 0; i < 16; i++) {
                int ii = (i + 4 * cg) & 15;
                const float4 hv = *(const float4*)(hbase + (ii << 2));
                a0 = fmaf(wreg[l][i * 4 + 0], hv.x, a0);
                a1 = fmaf(wreg[l][i * 4 + 1], hv.y, a1);
                a2 = fmaf(wreg[l][i * 4 + 2], hv.z, a2);
                a3 = fmaf(wreg[l][i * 4 + 3], hv.w, a3);
            }
            float acc = (a0 + a1) + (a2 + a3);
            // reduce the 4 cg-chunks (lanes j, j+16, j+32, j+48)
            acc += __shfl_xor(acc, 16);
            acc += __shfl_xor(acc, 32);
            if (lam < 16) lp[(j << 2) + w] = acc;   // [j][w], parity buffer
            __syncthreads();   // B2: lds_p complete

            if (t < 4) {
                // g[q] for hidden row 4k+t: sum lp[(t*4+q)*4 + w] over w
                const float4 p0 = *(const float4*)&lp[(t << 4) + 0];
                const float4 p1 = *(const float4*)&lp[(t << 4) + 4];
                const float4 p2 = *(const float4*)&lp[(t << 4) + 8];
                const float4 p3 = *(const float4*)&lp[(t << 4) + 12];
                float gi = (p0.x + p0.y) + (p0.z + p0.w) + xg0;
                float gf = (p1.x + p1.y) + (p1.z + p1.w) + xg1;
                float gG = (p2.x + p2.y) + (p2.z + p2.w) + xg2;
                float go = (p3.x + p3.y) + (p3.z + p3.w) + xg3;
                float cn = sigm_f(gf) * creg + sigm_f(gi) * tanh_f(gG);
                creg = cn;
                float hn = sigm_f(go) * tanh_f(cn);
                if (l == 3) hall[(size_t)step * 1024 + (k << 2) + t] = hn;
                uint64_t word = ((uint64_t)__float_as_uint(hn) << 32) | (uint64_t)(uint32_t)it;
                // private-line publish: WG k's 128B line, words (k<<4)+0..3
                __hip_atomic_store(&wb[(k << 4) + t], word,
                                   __ATOMIC_RELAXED, __HIP_MEMORY_SCOPE_AGENT);
            }
        }
    }
}

extern "C" void kernel_launch(void* const* d_in, const int* in_sizes, int n_in,
                              void* d_out, int out_size, void* d_ws, size_t ws_size,
                              hipStream_t stream)
{
    const float* x      = (const float*)d_in[0];
    const int*   ts     = (const int*)d_in[1];
    const float* proj_w = (const float*)d_in[2];
    const float* proj_b = (const float*)d_in[3];
    const float* te_w1  = (const float*)d_in[4];
    const float* te_b1  = (const float*)d_in[5];
    const float* te_w2  = (const float*)d_in[6];
    const float* te_b2  = (const float*)d_in[7];
    const float* Wih    = (const float*)d_in[8];
    const float* Whh    = (const float*)d_in[9];
    const float* bih    = (const float*)d_in[10];
    const float* bhh    = (const float*)d_in[11];
    const float* lin_w  = (const float*)d_in[12];
    const float* lin_b  = (const float*)d_in[13];
    float* out = (float*)d_out;

    char* ws = (char*)d_ws;
    const size_t MB16 = (size_t)NS * DT * 4;                    // 16 MiB
    float* bufA = (float*)ws;                                   // emb -> emb2 -> hall
    float* bufB = (float*)(ws + MB16);                          // h1 -> xp
    const size_t xg_f32_bytes  = (size_t)NS * 16384 * 4;        // 256 MiB
    const size_t xg_bf16_bytes = (size_t)NS * 16384 * 2;        // 128 MiB
    const size_t hbuf_bytes    = 2 * 4096 * sizeof(uint64_t);   // 64 KiB (private lines)
    const bool use_f32_xg = ws_size >= 2 * MB16 + xg_f32_bytes + hbuf_bytes + 64;
    float*          XGf = (float*)(ws + 2 * MB16);
    __hip_bfloat16* XGb = (__hip_bfloat16*)(ws + 2 * MB16);
    uint64_t* hbuf = (uint64_t*)(ws + 2 * MB16 +
                                 (use_f32_xg ? xg_f32_bytes : xg_bf16_bytes));

    hipMemsetAsync(hbuf, 0, hbuf_bytes, stream);

    // emb = sinusoidal(timesteps)
    emb_kernel<<<NS, 512, 0, stream>>>(ts, bufA);
    // h1 = silu(emb @ te_w1^T + te_b1)
    gemm_bt<true, false, 0><<<dim3(16, 32), 256, 0, stream>>>(
        bufA, te_w1, te_b1, nullptr, nullptr, bufB, nullptr, NS, DT, DT);
    // emb2 = h1 @ te_w2^T + te_b2
    gemm_bt<false, false, 0><<<dim3(16, 32), 256, 0, stream>>>(
        bufB, te_w2, te_b2, nullptr, nullptr, bufA, nullptr, NS, DT, DT);
    // xp = x @ proj_w^T + proj_b + emb2
    gemm_bt<false, true, 0><<<dim3(16, 32), 256, 0, stream>>>(
        x, proj_w, proj_b, nullptr, bufA, bufB, nullptr, NS, DT, DT);
    // XG[l] = xp @ Wih[l]^T + bih[l] + bhh[l]   (permuted layout), z = layer
    if (use_f32_xg) {
        gemm_bt<false, false, 2><<<dim3(64, 32, 4), 256, 0, stream>>>(
            bufB, Wih, bih, bhh, nullptr, XGf, nullptr, NS, H4, DT);
        seq_kernel<float><<<256, 256, 0, stream>>>(Whh, XGf, bufA, hbuf);
    } else {
        gemm_bt<false, false, 1><<<dim3(64, 32, 4), 256, 0, stream>>>(
            bufB, Wih, bih, bhh, nullptr, nullptr, XGb, NS, H4, DT);
        seq_kernel<__hip_bfloat16><<<256, 256, 0, stream>>>(Whh, XGb, bufA, hbuf);
    }
    // out = hall @ lin_w^T + lin_b
    gemm_bt<false, false, 0><<<dim3(16, 32), 256, 0, stream>>>(
        bufA, lin_w, lin_b, nullptr, nullptr, out, nullptr, NS, DT, DT);
}

// Round 12
// 41515.656 us; speedup vs baseline: 1.0442x; 1.0442x over previous
//
#include <hip/hip_runtime.h>
#include <hip/hip_bf16.h>
#include <stdint.h>

#define NS 4096     // samples / time steps
#define DT 1024     // dim_t == hidden == in
#define H4 4096     // 4*HID

// ---------- math helpers ----------
__device__ __forceinline__ float sigm_f(float x) { return 1.f / (1.f + __expf(-x)); }
__device__ __forceinline__ float tanh_f(float x) {
    float ax = fminf(fabsf(x), 15.f);                 // overflow-safe
    float t = 1.f - 2.f / (__expf(2.f * ax) + 1.f);
    return copysignf(t, x);
}

// ---------- sinusoidal embedding ----------
__global__ void emb_kernel(const int* __restrict__ ts, float* __restrict__ emb) {
    int t = blockIdx.x;
    int i = threadIdx.x;                 // 0..511
    float tv = (float)ts[t];
    const float c = -0.018024149455922082f;  // -ln(10000)/511
    float f = __expf(c * (float)i);
    float a = tv * f;
    float s, co;
    sincosf(a, &s, &co);
    emb[(size_t)t * DT + i] = s;
    emb[(size_t)t * DT + 512 + i] = co;
}

// ---------- generic C = A(M,K) @ B(Nc,K)^T + bias [+bias2] [+skip] [silu] ----------
// BM=128, BN=64, BK=16, 256 threads, each thread 8x4 outputs.
// XGMODE: 0 = plain fp32 C; 1 = bf16 XG layout; 2 = fp32 XG layout.
// XG layout per epoch (4096 elems): pos = k*16 + r*4 + q for col = q*1024 + 4k + r.
template <bool SILU, bool SKIP, int XGMODE>
__global__ __launch_bounds__(256) void gemm_bt(
    const float* __restrict__ A, const float* __restrict__ B,
    const float* __restrict__ bias, const float* __restrict__ bias2,
    const float* __restrict__ skip, float* __restrict__ Cf,
    __hip_bfloat16* __restrict__ Cb, int M, int Nc, int K)
{
    __shared__ __align__(16) float As[16][132];
    __shared__ __align__(16) float Bs[16][68];
    const int bn = blockIdx.x, bm = blockIdx.y, lz = blockIdx.z;
    if (XGMODE) {
        B     += (size_t)lz * H4 * DT;
        bias  += (size_t)lz * H4;
        bias2 += (size_t)lz * H4;
    }
    const int tid = threadIdx.x;
    const int tr = tid >> 4, tc = tid & 15;
    const int alr = tid >> 1, alc = (tid & 1) << 3;   // A: 128 rows x 16 cols
    const int blr = tid >> 2, blc = (tid & 3) << 2;   // B: 64 rows x 16 cols
    const float* Ap = A + (size_t)(bm * 128 + alr) * K + alc;
    const float* Bp = B + (size_t)(bn * 64 + blr) * K + blc;

    float acc[8][4];
#pragma unroll
    for (int i = 0; i < 8; i++)
#pragma unroll
        for (int j = 0; j < 4; j++) acc[i][j] = 0.f;

    for (int kk = 0; kk < K; kk += 16) {
        float4 a0 = *(const float4*)(Ap + kk);
        float4 a1 = *(const float4*)(Ap + kk + 4);
        float4 b0 = *(const float4*)(Bp + kk);
        __syncthreads();
        As[alc + 0][alr] = a0.x; As[alc + 1][alr] = a0.y;
        As[alc + 2][alr] = a0.z; As[alc + 3][alr] = a0.w;
        As[alc + 4][alr] = a1.x; As[alc + 5][alr] = a1.y;
        As[alc + 6][alr] = a1.z; As[alc + 7][alr] = a1.w;
        Bs[blc + 0][blr] = b0.x; Bs[blc + 1][blr] = b0.y;
        Bs[blc + 2][blr] = b0.z; Bs[blc + 3][blr] = b0.w;
        __syncthreads();
#pragma unroll
        for (int k = 0; k < 16; k++) {
            const float4 av0 = *(const float4*)&As[k][tr * 8];
            const float4 av1 = *(const float4*)&As[k][tr * 8 + 4];
            const float4 bv  = *(const float4*)&Bs[k][tc * 4];
            float aa[8] = {av0.x, av0.y, av0.z, av0.w, av1.x, av1.y, av1.z, av1.w};
            float bb[4] = {bv.x, bv.y, bv.z, bv.w};
#pragma unroll
            for (int i = 0; i < 8; i++)
#pragma unroll
                for (int j = 0; j < 4; j++)
                    acc[i][j] = fmaf(aa[i], bb[j], acc[i][j]);
        }
    }

#pragma unroll
    for (int i = 0; i < 8; i++) {
        int row = bm * 128 + tr * 8 + i;
#pragma unroll
        for (int j = 0; j < 4; j++) {
            int col = bn * 64 + tc * 4 + j;
            float v = acc[i][j] + bias[col];
            if (XGMODE) v += bias2[col];
            if (SKIP)   v += skip[(size_t)row * Nc + col];
            if (SILU)   v = v * (1.f / (1.f + __expf(-v)));
            if (XGMODE) {
                int q = col >> 10, jj = col & 1023;
                size_t idx = (size_t)row * 16384 + (size_t)lz * 4096
                           + ((size_t)(jj >> 2) << 4) + ((jj & 3) << 2) + q;
                if (XGMODE == 2) Cf[idx] = v;
                else             Cb[idx] = __float2bfloat16(v);
            } else {
                Cf[(size_t)row * Nc + col] = v;
            }
        }
    }
}

// ---------- persistent sequential LSTM chain ----------
// SESSION-BEST STRUCTURE (r9, 39.24ms seq / 41.56ms total): r0 broadcast-dot
// + private-line hbuf. 256 WGs x 256 threads; WG k owns h/c rows [4k,4k+4).
// Dot mapping (broadcast-optimized): lane = (j = t&15, cg = (t>>4)&3), wave w.
// Lane computes g-row d=j (r=j>>2, q=j&3, grow=q*1024+4k+r) over cols
// 256w + 64cg + [0,64). The 16 lanes sharing cg read the SAME LDS address
// -> free broadcast. Rotation (i+4cg)&15 keeps residual conflicts 2-way.
// Cross-wave reduce via 64-float lds_p + B2; gates+publish by threads t<4 of
// wave 0 -> one coalesced 32B store.
// PRIVATE-LINE hbuf [2][256][16] u64 (r7/r9-verified): WG k's 4 rows occupy
// bytes 0..31 of its OWN 128B line-aligned region -> sole writer per line,
// no cross-XCD same-line write interleave (r2 calibration: ~700cy per
// serialized same-line transaction). Poll word for row m*256+t:
// (m<<10) + ((t>>2)<<4) + (t&3).
// Evidence trail (final): r2 bank conflicts free (same-addr broadcast);
// r3 publish coalescing verified via WRITE_SIZE; r5 poll-rate backoff and
// fold reduction both null; r6 1024-thread blocked by regsPerBlock=131072;
// r7/r9 private lines -0.8..-3.4ms; r11 wave-affinity/B1-removal REGRESSED
// +2ms (B1's phase discipline -- parallel detect, then parallel dot -- is
// worth more than the barrier costs). The epoch period (~5750cy = 2.40us)
// is the chip-wide 4KB all-gather + agent-scope publish->detect round trip
// + 256-WG straggler max; weight residency (256KB/WG of VGPRs) forces the
// 256-WG layout, and the (h,c) carry makes the 16384-cell chain serial.
// Deadlock-free: slot for epoch e is only overwritten at e+2, which requires
// all WGs published e+1, which requires all WGs consumed e.
template <typename XT>
__global__ __launch_bounds__(256, 1) void seq_kernel(
    const float* __restrict__ Whh,            // [4][4096][1024]
    const XT* __restrict__ XG,                // [epoch][k*16 + r*4 + q]
    float* __restrict__ hall,                 // [4096][1024]
    uint64_t* hbuf)                           // [2][256][16]
{
    const int k = blockIdx.x;
    const int t = threadIdx.x;
    const int j = t & 15;                     // g-row index d
    const int cg = (t >> 4) & 3;              // 64-col sub-chunk
    const int w = t >> 6;                     // wave id
    const int q = j & 3, r = j >> 2;
    const int grow = q * 1024 + 4 * k + r;

    // weights, rotated to match the rotated LDS reads:
    // wreg[l][i*4+e] = Whh[l][grow][256w + 64cg + 4*((i+4cg)&15) + e]
    float wreg[4][64];
#pragma unroll
    for (int l = 0; l < 4; l++) {
        const float* src = Whh + ((size_t)l * H4 + grow) * 1024 + (w << 8) + (cg << 6);
#pragma unroll
        for (int i = 0; i < 16; i++) {
            int ii = (i + 4 * cg) & 15;
            float4 v = *(const float4*)(src + (ii << 2));
            wreg[l][i * 4 + 0] = v.x; wreg[l][i * 4 + 1] = v.y;
            wreg[l][i * 4 + 2] = v.z; wreg[l][i * 4 + 3] = v.w;
        }
    }

    __shared__ __align__(16) float lh[1024];
    __shared__ __align__(16) float lds_p[64];
    float creg = 0.f;   // c for row 4k+t (threads t<4 only)

    // poll word index for m-th staged row (row = m*256 + t):
    //   line = (m<<6)+(t>>2), slot = t&3 -> word (m<<10) + ((t>>2)<<4) + (t&3)
    const int pw = ((t >> 2) << 4) + (t & 3);

    for (int step = 0; step < NS; ++step) {
#pragma unroll
        for (int l = 0; l < 4; l++) {
            const int it = step * 4 + l + 1;             // epoch being produced
            const uint32_t rtag = (uint32_t)(it - 1);
            uint64_t* rb = (l & 1) ? (hbuf + 4096) : hbuf;        // (it-1)&1 == l&1
            uint64_t* wb = ((l + 1) & 1) ? (hbuf + 4096) : hbuf;  // it&1

            // ---- XG prefetch by gate threads, issued BEFORE polling
            float xg0 = 0.f, xg1 = 0.f, xg2 = 0.f, xg3 = 0.f;
            if (t < 4) {
                const XT* p = XG + (size_t)(it - 1) * H4 + (k << 4) + (t << 2);
                if constexpr (sizeof(XT) == 4) {
                    float4 v = *(const float4*)p;
                    xg0 = v.x; xg1 = v.y; xg2 = v.z; xg3 = v.w;
                } else {
                    ushort4 v = *(const ushort4*)p;
                    xg0 = __uint_as_float((uint32_t)v.x << 16);
                    xg1 = __uint_as_float((uint32_t)v.y << 16);
                    xg2 = __uint_as_float((uint32_t)v.z << 16);
                    xg3 = __uint_as_float((uint32_t)v.w << 16);
                }
            }

            // ---- poll + stage (thread t owns rows t, 256+t, 512+t, 768+t)
            uint32_t got = 0;
            while (got != 0xFu) {
#pragma unroll
                for (int m = 0; m < 4; m++) {
                    if (!(got & (1u << m))) {
                        uint64_t u = __hip_atomic_load(&rb[(m << 10) + pw],
                                                       __ATOMIC_RELAXED, __HIP_MEMORY_SCOPE_AGENT);
                        if ((uint32_t)u == rtag) {
                            lh[(m << 8) + t] = __uint_as_float((uint32_t)(u >> 32));
                            got |= (1u << m);
                        }
                    }
                }
            }
            __syncthreads();   // B1: lh complete

            // ---- broadcast dot: 16 lanes/address, rotated, 4 accumulators
            const float* hbase = lh + (w << 8) + (cg << 6);
            float a0 = 0.f, a1 = 0.f, a2 = 0.f, a3 = 0.f;
#pragma unroll
            for (int i = 0; i < 16; i++) {
                int ii = (i + 4 * cg) & 15;
                const float4 hv = *(const float4*)(hbase + (ii << 2));
                a0 = fmaf(wreg[l][i * 4 + 0], hv.x, a0);
                a1 = fmaf(wreg[l][i * 4 + 1], hv.y, a1);
                a2 = fmaf(wreg[l][i * 4 + 2], hv.z, a2);
                a3 = fmaf(wreg[l][i * 4 + 3], hv.w, a3);
            }
            float acc = (a0 + a1) + (a2 + a3);
            // reduce the 4 cg-chunks (lanes j, j+16, j+32, j+48)
            acc += __shfl_xor(acc, 16);
            acc += __shfl_xor(acc, 32);
            if ((t & 63) < 16) lds_p[(j << 2) + w] = acc;   // [j][w]
            __syncthreads();   // B2: lds_p complete

            if (t < 4) {
                // g[q] for hidden row 4k+t: sum lds_p[(t*4+q)*4 + w] over w
                const float4 p0 = *(const float4*)&lds_p[(t << 4) + 0];
                const float4 p1 = *(const float4*)&lds_p[(t << 4) + 4];
                const float4 p2 = *(const float4*)&lds_p[(t << 4) + 8];
                const float4 p3 = *(const float4*)&lds_p[(t << 4) + 12];
                float gi = (p0.x + p0.y) + (p0.z + p0.w) + xg0;
                float gf = (p1.x + p1.y) + (p1.z + p1.w) + xg1;
                float gG = (p2.x + p2.y) + (p2.z + p2.w) + xg2;
                float go = (p3.x + p3.y) + (p3.z + p3.w) + xg3;
                float cn = sigm_f(gf) * creg + sigm_f(gi) * tanh_f(gG);
                creg = cn;
                float hn = sigm_f(go) * tanh_f(cn);
                if (l == 3) hall[(size_t)step * 1024 + (k << 2) + t] = hn;
                uint64_t word = ((uint64_t)__float_as_uint(hn) << 32) | (uint64_t)(uint32_t)it;
                // private-line publish: WG k's 128B line, words (k<<4)+0..3
                __hip_atomic_store(&wb[(k << 4) + t], word,
                                   __ATOMIC_RELAXED, __HIP_MEMORY_SCOPE_AGENT);
            }
        }
    }
}

extern "C" void kernel_launch(void* const* d_in, const int* in_sizes, int n_in,
                              void* d_out, int out_size, void* d_ws, size_t ws_size,
                              hipStream_t stream)
{
    const float* x      = (const float*)d_in[0];
    const int*   ts     = (const int*)d_in[1];
    const float* proj_w = (const float*)d_in[2];
    const float* proj_b = (const float*)d_in[3];
    const float* te_w1  = (const float*)d_in[4];
    const float* te_b1  = (const float*)d_in[5];
    const float* te_w2  = (const float*)d_in[6];
    const float* te_b2  = (const float*)d_in[7];
    const float* Wih    = (const float*)d_in[8];
    const float* Whh    = (const float*)d_in[9];
    const float* bih    = (const float*)d_in[10];
    const float* bhh    = (const float*)d_in[11];
    const float* lin_w  = (const float*)d_in[12];
    const float* lin_b  = (const float*)d_in[13];
    float* out = (float*)d_out;

    char* ws = (char*)d_ws;
    const size_t MB16 = (size_t)NS * DT * 4;                    // 16 MiB
    float* bufA = (float*)ws;                                   // emb -> emb2 -> hall
    float* bufB = (float*)(ws + MB16);                          // h1 -> xp
    const size_t xg_f32_bytes  = (size_t)NS * 16384 * 4;        // 256 MiB
    const size_t xg_bf16_bytes = (size_t)NS * 16384 * 2;        // 128 MiB
    const size_t hbuf_bytes    = 2 * 4096 * sizeof(uint64_t);   // 64 KiB (private lines)
    const bool use_f32_xg = ws_size >= 2 * MB16 + xg_f32_bytes + hbuf_bytes + 64;
    float*          XGf = (float*)(ws + 2 * MB16);
    __hip_bfloat16* XGb = (__hip_bfloat16*)(ws + 2 * MB16);
    uint64_t* hbuf = (uint64_t*)(ws + 2 * MB16 +
                                 (use_f32_xg ? xg_f32_bytes : xg_bf16_bytes));

    hipMemsetAsync(hbuf, 0, hbuf_bytes, stream);

    // emb = sinusoidal(timesteps)
    emb_kernel<<<NS, 512, 0, stream>>>(ts, bufA);
    // h1 = silu(emb @ te_w1^T + te_b1)
    gemm_bt<true, false, 0><<<dim3(16, 32), 256, 0, stream>>>(
        bufA, te_w1, te_b1, nullptr, nullptr, bufB, nullptr, NS, DT, DT);
    // emb2 = h1 @ te_w2^T + te_b2
    gemm_bt<false, false, 0><<<dim3(16, 32), 256, 0, stream>>>(
        bufB, te_w2, te_b2, nullptr, nullptr, bufA, nullptr, NS, DT, DT);
    // xp = x @ proj_w^T + proj_b + emb2
    gemm_bt<false, true, 0><<<dim3(16, 32), 256, 0, stream>>>(
        x, proj_w, proj_b, nullptr, bufA, bufB, nullptr, NS, DT, DT);
    // XG[l] = xp @ Wih[l]^T + bih[l] + bhh[l]   (permuted layout), z = layer
    if (use_f32_xg) {
        gemm_bt<false, false, 2><<<dim3(64, 32, 4), 256, 0, stream>>>(
            bufB, Wih, bih, bhh, nullptr, XGf, nullptr, NS, H4, DT);
        seq_kernel<float><<<256, 256, 0, stream>>>(Whh, XGf, bufA, hbuf);
    } else {
        gemm_bt<false, false, 1><<<dim3(64, 32, 4), 256, 0, stream>>>(
            bufB, Wih, bih, bhh, nullptr, nullptr, XGb, NS, H4, DT);
        seq_kernel<__hip_bfloat16><<<256, 256, 0, stream>>>(Whh, XGb, bufA, hbuf);
    }
    // out = hall @ lin_w^T + lin_b
    gemm_bt<false, false, 0><<<dim3(16, 32), 256, 0, stream>>>(
        bufA, lin_w, lin_b, nullptr, nullptr, out, nullptr, NS, DT, DT);
}